// Round 2
// baseline (174.923 us; speedup 1.0000x reference)
//
#include <hip/hip_runtime.h>

#define HH 256
#define WW 256
#define NPIX (2 * HH * WW)   // 131072 (B=2)
#define NC 48
#define NB 31
#define NG 6          // channel groups
#define CG 8          // channels per group (NG*CG == NC)
#define OT 32         // output tile (32x32 per block)
#define PT 38         // phi tile = OT+6
#define PSTR 40       // phi LDS row stride (16B-aligned rows)
#define UT 44         // u tile = OT+12
#define USTR 48       // u LDS row stride (16B-aligned rows)

// Fused: conv1(7x7) -> RBF(31 gaussians) -> conv2(flipped 7x7), 8 channels/block.
// All data f32 (per reference). Weights read directly from global via
// block-uniform indices -> scalar s_load, L2-resident across all 768 blocks.
__global__ __launch_bounds__(256)
void tnrd_main(const float* __restrict__ u,
               const float* __restrict__ wf,   // filters [48][49]
               const float* __restrict__ wr,   // rbf weights [48][31]
               float* __restrict__ part)
{
    __shared__ __align__(16) float u_s[UT * USTR];
    __shared__ __align__(16) float phi_s[2][PT * PSTR];

    const int tid = threadIdx.x;
    const int bx = blockIdx.x, by = blockIdx.y;
    const int b = blockIdx.z / NG, g = blockIdx.z % NG;
    const int c0 = g * CG;

    // ---- stage u tile (6-halo, zero-padded) into LDS; pad cols also zeroed ----
    const int uy0 = by * OT - 6, ux0 = bx * OT - 6;
    const float* ub = u + b * (HH * WW);
    for (int i = tid; i < UT * USTR; i += 256) {
        int r = i / USTR, c = i - r * USTR;
        int gy = uy0 + r, gx = ux0 + c;
        float v = 0.f;
        if (c < UT && (unsigned)gy < HH && (unsigned)gx < WW)
            v = ub[gy * WW + gx];
        u_s[i] = v;
    }
    __syncthreads();

    const int oy = tid >> 3;        // 0..31
    const int ox0 = (tid & 7) * 4;  // 0..28 : 4 adjacent outputs per thread
    float o0 = 0.f, o1 = 0.f, o2 = 0.f, o3 = 0.f;

    const int py0 = by * OT - 3, px0 = bx * OT - 3;  // phi-tile global origin

    for (int ci = 0; ci < CG; ++ci) {
        const int c = c0 + ci;
        const float* wc = wf + c * 49;   // block-uniform -> scalar loads
        const float* rc = wr + c * NB;   // block-uniform -> scalar loads
        float* pb = phi_s[ci & 1];

        // ---- phi tile: 38 rows x 10 col-groups of 4 (cols 38,39 = pad) ----
        for (int gi = tid; gi < PT * 10; gi += 256) {
            int pr = gi / 10;
            int pc = (gi - pr * 10) * 4;
            float a0 = 0.f, a1 = 0.f, a2 = 0.f, a3 = 0.f;
            #pragma unroll
            for (int dy = 0; dy < 7; ++dy) {
                const float* row = &u_s[(pr + dy) * USTR + pc];
                float sv[12];
                #pragma unroll
                for (int j = 0; j < 12; ++j) sv[j] = row[j];  // 3x ds_read_b128
                #pragma unroll
                for (int dx = 0; dx < 7; ++dx) {
                    float w = wc[dy * 7 + dx];
                    a0 = fmaf(sv[dx],     w, a0);
                    a1 = fmaf(sv[dx + 1], w, a1);
                    a2 = fmaf(sv[dx + 2], w, a2);
                    a3 = fmaf(sv[dx + 3], w, a3);
                }
            }
            float cv[4] = {a0, a1, a2, a3};
            float ph[4];
            #pragma unroll
            for (int j = 0; j < 4; ++j) {
                float x = cv[j];
                float acc = 0.f;
                #pragma unroll
                for (int k = 0; k < NB; ++k) {
                    float mu = -1.f + (float)k * (1.f / 15.f);
                    float d = x - mu;
                    acc = fmaf(rc[k], __expf(-50.f * d * d), acc);
                }
                // phi is zero OUTSIDE the image for conv2's zero padding
                // (RBF output at padding must be 0, not RBF(0))
                int gy = py0 + pr, gx = px0 + pc + j;
                ph[j] = ((unsigned)gy < HH && (unsigned)gx < WW) ? acc : 0.f;
            }
            float* dst = &pb[pr * PSTR + pc];
            #pragma unroll
            for (int j = 0; j < 4; ++j) dst[j] = ph[j];  // ds_write_b128
        }
        __syncthreads();
        // Double-buffered phi: iteration ci+1 writes the other buffer, and the
        // barrier inside ci+1 orders those reads before ci+2 rewrites this one.

        // ---- accumulate diffusion with spatially-flipped weights ----
        #pragma unroll
        for (int dy = 0; dy < 7; ++dy) {
            const float* prow = &pb[(oy + dy) * PSTR + ox0];
            float sv[10];
            #pragma unroll
            for (int j = 0; j < 10; ++j) sv[j] = prow[j];
            #pragma unroll
            for (int dx = 0; dx < 7; ++dx) {
                float w = wc[(6 - dy) * 7 + (6 - dx)];
                o0 = fmaf(sv[dx],     w, o0);
                o1 = fmaf(sv[dx + 1], w, o1);
                o2 = fmaf(sv[dx + 2], w, o2);
                o3 = fmaf(sv[dx + 3], w, o3);
            }
        }
    }

    const int gy = by * OT + oy, gx = bx * OT + ox0;
    float4 v4 = make_float4(o0, o1, o2, o3);
    *reinterpret_cast<float4*>(part + (size_t)g * NPIX + b * (HH * WW)
                               + gy * WW + gx) = v4;
}

__global__ __launch_bounds__(256)
void combine_kernel(const float* __restrict__ u,
                    const float* __restrict__ f,
                    const float* __restrict__ lam,
                    const float* __restrict__ part,
                    float* __restrict__ out)
{
    int i = blockIdx.x * 256 + threadIdx.x;  // grid = 512 blocks -> NPIX
    float d = 0.f;
    #pragma unroll
    for (int g = 0; g < NG; ++g) d += part[g * NPIX + i];
    float lv = lam[0];
    float uv = u[i];
    float fv = f[i];
    out[i] = uv - d - lv * (uv - fv);
}

extern "C" void kernel_launch(void* const* d_in, const int* in_sizes, int n_in,
                              void* d_out, int out_size, void* d_ws, size_t ws_size,
                              hipStream_t stream) {
    const float* u    = (const float*)d_in[0];
    const float* f    = (const float*)d_in[1];
    const float* filt = (const float*)d_in[2];
    const float* rbfw = (const float*)d_in[3];
    const float* lam  = (const float*)d_in[4];
    float* out = (float*)d_out;
    float* part = (float*)d_ws;  // 6 * 131072 f32 partial sums (~3.1 MB)

    tnrd_main<<<dim3(8, 8, 2 * NG), 256, 0, stream>>>(u, filt, rbfw, part);
    combine_kernel<<<512, 256, 0, stream>>>(u, f, lam, part, out);
}